// Round 1
// baseline (4361.963 us; speedup 1.0000x reference)
//
#include <hip/hip_runtime.h>
#include <math.h>

#define BB 64
#define NN 512
#define KK 16

__device__ __forceinline__ double gelu64(double x) {
    return 0.5 * x * (1.0 + erf(x * 0.70710678118654752440084436210485));
}
__device__ __forceinline__ float gelu32(float x) {
    return 0.5f * x * (1.0f + erff(x * 0.70710678118654752440f));
}

// ---------------------------------------------------------------------------
// Block-1 kNN: F=3 points (+999 mask shift), f64 distances, top-17 drop-first.
// One 64-thread block per (b, n) row.
// ---------------------------------------------------------------------------
__global__ __launch_bounds__(64) void knn1(const float* __restrict__ points,
                                           const int* __restrict__ mask,
                                           int* __restrict__ idx_out) {
    __shared__ double qs[NN * 3];   // 12 KB
    __shared__ double dist[NN];     // 4 KB
    const int bn = blockIdx.x;
    const int b = bn >> 9;
    const int n = bn & 511;
    const int tid = threadIdx.x;

    for (int m = tid; m < NN; m += 64) {
        double sh = (mask[b * NN + m] == 0) ? 999.0 : 0.0;
        const float* p = points + ((size_t)b * NN + m) * 3;
        qs[m * 3 + 0] = (double)p[0] + sh;
        qs[m * 3 + 1] = (double)p[1] + sh;
        qs[m * 3 + 2] = (double)p[2] + sh;
    }
    __syncthreads();

    const double qn0 = qs[n * 3 + 0], qn1 = qs[n * 3 + 1], qn2 = qs[n * 3 + 2];
    const double rn = qn0 * qn0 + qn1 * qn1 + qn2 * qn2;
    for (int i = 0; i < 8; ++i) {
        int m = tid + 64 * i;
        double m0 = qs[m * 3 + 0], m1 = qs[m * 3 + 1], m2 = qs[m * 3 + 2];
        double rm = m0 * m0 + m1 * m1 + m2 * m2;
        double dt = qn0 * m0 + qn1 * m1 + qn2 * m2;
        dist[m] = (rn - 2.0 * dt) + rm + 1e-5;
    }
    __syncthreads();

    // 17 iterations of (distance, index)-lexicographic argmin; drop the first.
    for (int it = 0; it <= KK; ++it) {
        double bd = 1e300;
        int bi = NN;
        for (int i = 0; i < 8; ++i) {
            int m = tid + 64 * i;           // ascending m: strict < keeps smallest index on ties
            double d = dist[m];
            if (d < bd) { bd = d; bi = m; }
        }
        for (int off = 32; off > 0; off >>= 1) {
            double od = __shfl_xor(bd, off, 64);
            int    oi = __shfl_xor(bi, off, 64);
            if (od < bd || (od == bd && oi < bi)) { bd = od; bi = oi; }
        }
        if (tid == 0) {
            dist[bi] = 1e300;
            if (it > 0) idx_out[(size_t)bn * KK + (it - 1)] = bi;
        }
        __syncthreads();
    }
}

// ---------------------------------------------------------------------------
// Block-1 MLP in f64 (its output feeds block-2 distance ordering).
// x:(B,N,32)  W1:(64,128) W2:(128,64)  -> feats1:(B,N,64) f64
// One 256-thread block per (b, n).
// ---------------------------------------------------------------------------
__global__ __launch_bounds__(256) void mlp1_f64(const float* __restrict__ x,
                                                const int* __restrict__ idx,
                                                const float* __restrict__ W1,
                                                const float* __restrict__ b1,
                                                const float* __restrict__ W2,
                                                const float* __restrict__ b2,
                                                double* __restrict__ feats_out) {
    const int C = 32;
    __shared__ double ctr[32];
    __shared__ double edg[KK][32];
    __shared__ double H1[KK][128];
    __shared__ double H2s[KK][64];
    const int bn = blockIdx.x;
    const int b = bn >> 9;
    const int tid = threadIdx.x;

    if (tid < C) ctr[tid] = (double)x[(size_t)bn * C + tid];
    __syncthreads();
    for (int e = tid; e < KK * C; e += 256) {
        int k = e >> 5, c = e & 31;
        int m = idx[bn * KK + k];
        edg[k][c] = (double)x[((size_t)b * NN + m) * C + c] - ctr[c];
    }
    __syncthreads();

    {   // layer 1: H1[k][j], j<128; thread -> (j = tid&127, k-block of 8)
        const int j = tid & 127;
        const int kb = (tid >> 7) * 8;
        double cterm = (double)b1[j];
        for (int c = 0; c < C; ++c) cterm += ctr[c] * (double)W1[(C + c) * 128 + j];
        double acc[8];
        #pragma unroll
        for (int kk = 0; kk < 8; ++kk) acc[kk] = cterm;
        for (int c = 0; c < C; ++c) {
            double w = (double)W1[c * 128 + j];
            #pragma unroll
            for (int kk = 0; kk < 8; ++kk) acc[kk] += edg[kb + kk][c] * w;
        }
        #pragma unroll
        for (int kk = 0; kk < 8; ++kk) H1[kb + kk][j] = gelu64(acc[kk]);
    }
    __syncthreads();

    {   // layer 2: H2[k][j], j<64; thread -> (j = tid&63, k-block of 4)
        const int j = tid & 63;
        const int kb = (tid >> 6) * 4;
        double acc[4];
        #pragma unroll
        for (int kk = 0; kk < 4; ++kk) acc[kk] = (double)b2[j];
        for (int c = 0; c < 128; ++c) {
            double w = (double)W2[c * 64 + j];
            #pragma unroll
            for (int kk = 0; kk < 4; ++kk) acc[kk] += H1[kb + kk][c] * w;
        }
        #pragma unroll
        for (int kk = 0; kk < 4; ++kk) H2s[kb + kk][j] = gelu64(acc[kk]);
    }
    __syncthreads();

    if (tid < 64) {
        double s = 0.0;
        for (int k = 0; k < KK; ++k) s += H2s[k][tid];
        feats_out[(size_t)bn * 64 + tid] = s * 0.0625;
    }
}

// ---------------------------------------------------------------------------
// Block-2 kNN: F=64 feats (+999 mask shift), f64 distances, top-17 drop-first.
// One 256-thread block per (b, n); each thread handles 2 candidates.
// ---------------------------------------------------------------------------
__global__ __launch_bounds__(256) void knn2(const double* __restrict__ feats,
                                            const int* __restrict__ mask,
                                            int* __restrict__ idx_out) {
    __shared__ double qn[64];
    __shared__ double dist[NN];
    __shared__ double wd[4];
    __shared__ int    wi[4];
    const int bn = blockIdx.x;
    const int b = bn >> 9;
    const int tid = threadIdx.x;

    if (tid < 64) {
        double sh = (mask[bn] == 0) ? 999.0 : 0.0;
        qn[tid] = feats[(size_t)bn * 64 + tid] + sh;
    }
    __syncthreads();

    double rn = 0.0;
    for (int f = 0; f < 64; ++f) rn += qn[f] * qn[f];

    for (int i = 0; i < 2; ++i) {
        int m = tid + 256 * i;
        double sh = (mask[b * NN + m] == 0) ? 999.0 : 0.0;
        const double* qm = feats + ((size_t)b * NN + m) * 64;
        double rm = 0.0, dt = 0.0;
        for (int f = 0; f < 64; ++f) {
            double v = qm[f] + sh;
            rm += v * v;
            dt += qn[f] * v;
        }
        dist[m] = (rn - 2.0 * dt) + rm + 1e-5;
    }
    __syncthreads();

    for (int it = 0; it <= KK; ++it) {
        double bd = 1e300;
        int bi = NN;
        for (int i = 0; i < 2; ++i) {
            int m = tid + 256 * i;          // ascending m
            double d = dist[m];
            if (d < bd) { bd = d; bi = m; }
        }
        for (int off = 32; off > 0; off >>= 1) {
            double od = __shfl_xor(bd, off, 64);
            int    oi = __shfl_xor(bi, off, 64);
            if (od < bd || (od == bd && oi < bi)) { bd = od; bi = oi; }
        }
        if ((tid & 63) == 0) { wd[tid >> 6] = bd; wi[tid >> 6] = bi; }
        __syncthreads();
        if (tid == 0) {
            double fbd = wd[0]; int fbi = wi[0];
            for (int w = 1; w < 4; ++w)
                if (wd[w] < fbd || (wd[w] == fbd && wi[w] < fbi)) { fbd = wd[w]; fbi = wi[w]; }
            dist[fbi] = 1e300;
            if (it > 0) idx_out[(size_t)bn * KK + (it - 1)] = fbi;
        }
        __syncthreads();
    }
}

// ---------------------------------------------------------------------------
// Block-2 MLP in f32 (no selection downstream), + mean + final mask multiply.
// feats1:(B,N,64) f64  W1:(128,128) W2:(128,64)  -> out:(B,N,64) f32
// ---------------------------------------------------------------------------
__global__ __launch_bounds__(256) void mlp2_f32(const double* __restrict__ feats,
                                                const int* __restrict__ idx,
                                                const float* __restrict__ W1,
                                                const float* __restrict__ b1,
                                                const float* __restrict__ W2,
                                                const float* __restrict__ b2,
                                                const int* __restrict__ mask,
                                                float* __restrict__ out) {
    const int C = 64;
    __shared__ float ctr[64];
    __shared__ float edg[KK][64];
    __shared__ float H1[KK][128];
    __shared__ float H2s[KK][64];
    const int bn = blockIdx.x;
    const int b = bn >> 9;
    const int tid = threadIdx.x;

    if (tid < C) ctr[tid] = (float)feats[(size_t)bn * C + tid];
    __syncthreads();
    for (int e = tid; e < KK * C; e += 256) {
        int k = e >> 6, c = e & 63;
        int m = idx[bn * KK + k];
        edg[k][c] = (float)feats[((size_t)b * NN + m) * C + c] - ctr[c];
    }
    __syncthreads();

    {   // layer 1
        const int j = tid & 127;
        const int kb = (tid >> 7) * 8;
        float cterm = b1[j];
        for (int c = 0; c < C; ++c) cterm += ctr[c] * W1[(C + c) * 128 + j];
        float acc[8];
        #pragma unroll
        for (int kk = 0; kk < 8; ++kk) acc[kk] = cterm;
        for (int c = 0; c < C; ++c) {
            float w = W1[c * 128 + j];
            #pragma unroll
            for (int kk = 0; kk < 8; ++kk) acc[kk] += edg[kb + kk][c] * w;
        }
        #pragma unroll
        for (int kk = 0; kk < 8; ++kk) H1[kb + kk][j] = gelu32(acc[kk]);
    }
    __syncthreads();

    {   // layer 2
        const int j = tid & 63;
        const int kb = (tid >> 6) * 4;
        float acc[4];
        #pragma unroll
        for (int kk = 0; kk < 4; ++kk) acc[kk] = b2[j];
        for (int c = 0; c < 128; ++c) {
            float w = W2[c * 64 + j];
            #pragma unroll
            for (int kk = 0; kk < 4; ++kk) acc[kk] += H1[kb + kk][c] * w;
        }
        #pragma unroll
        for (int kk = 0; kk < 4; ++kk) H2s[kb + kk][j] = gelu32(acc[kk]);
    }
    __syncthreads();

    if (tid < 64) {
        float s = 0.0f;
        for (int k = 0; k < KK; ++k) s += H2s[k][tid];
        s *= 0.0625f;
        if (mask[bn] == 0) s = 0.0f;
        out[(size_t)bn * 64 + tid] = s;
    }
}

extern "C" void kernel_launch(void* const* d_in, const int* in_sizes, int n_in,
                              void* d_out, int out_size, void* d_ws, size_t ws_size,
                              hipStream_t stream) {
    const float* x      = (const float*)d_in[0];
    const float* points = (const float*)d_in[1];
    const int*   mask   = (const int*)d_in[2];
    const float* W1_0 = (const float*)d_in[3];
    const float* b1_0 = (const float*)d_in[4];
    const float* W2_0 = (const float*)d_in[5];
    const float* b2_0 = (const float*)d_in[6];
    const float* W1_1 = (const float*)d_in[7];
    const float* b1_1 = (const float*)d_in[8];
    const float* W2_1 = (const float*)d_in[9];
    const float* b2_1 = (const float*)d_in[10];

    int*    idx    = (int*)d_ws;                                        // 2 MB
    double* feats1 = (double*)((char*)d_ws + (size_t)BB * NN * KK * 4); // 16.8 MB

    dim3 grid(BB * NN);
    knn1<<<grid, 64, 0, stream>>>(points, mask, idx);
    mlp1_f64<<<grid, 256, 0, stream>>>(x, idx, W1_0, b1_0, W2_0, b2_0, feats1);
    knn2<<<grid, 256, 0, stream>>>(feats1, mask, idx);
    mlp2_f32<<<grid, 256, 0, stream>>>(feats1, idx, W1_1, b1_1, W2_1, b2_1, mask, (float*)d_out);
}